// Round 7
// baseline (1006.797 us; speedup 1.0000x reference)
//
#include <hip/hip_runtime.h>

#define NU 200000
#define NR 50000
#define DD 64
#define NE 2000000
#define NQ 500000
#define NBR 196   // ceil(NR/256)
#define NBU 782   // ceil(NU/256)
#define LDW 68    // padded LDS row stride (68*4B=272B: 16B-aligned, bank-shift 4)

// ---- dst-windowed CSR build parameters ----
#define NBS 98              // dst windows per side
#define BKT_CAP 24576       // pair capacity per window (mean 20480, +28 sigma)
#define LW_U 11             // 2048 users per window
#define LW_R 9              // 512 restaurants per window
#define PB_E 4096           // edges per binpass block
#define NPBB 489            // ceil(NE / PB_E)

// -------------------- binpass: bin (src,dst) pairs by dst window -----------
__global__ __launch_bounds__(256)
void binpass_kernel(const int* __restrict__ ru_src, const int* __restrict__ ru_dst,
                    const int* __restrict__ ur_src, const int* __restrict__ ur_dst,
                    int* __restrict__ bcur, int2* __restrict__ pairs) {
    __shared__ int2 stg[PB_E];
    __shared__ unsigned char gstg[PB_E];
    __shared__ int hist[256];
    __shared__ int sca[256], scb[256];
    __shared__ int gpos[128];
    int side = (blockIdx.x >= NPBB) ? 1 : 0;
    int blk = side ? (blockIdx.x - NPBB) : blockIdx.x;
    const int* src = side ? ur_src : ru_src;
    const int* dst = side ? ur_dst : ru_dst;
    int lw = side ? LW_R : LW_U;
    int* bc = bcur + side * NBS;
    int2* region = pairs + (size_t)side * NBS * BKT_CAP;
    int tid = threadIdx.x;
    hist[tid] = 0;
    __syncthreads();
    int base = blk * PB_E;
    int myg[16]; int myrank[16]; int2 myp[16];
#pragma unroll
    for (int i = 0; i < 16; i++) {
        int e = base + i * 256 + tid;
        if (e < NE) {
            int d = dst[e];
            int g = d >> lw;
            myg[i] = g;
            myp[i] = make_int2(src[e], d);
            myrank[i] = atomicAdd(&hist[g], 1);
        } else myg[i] = -1;
    }
    __syncthreads();
    int h = hist[tid];
    sca[tid] = h;
    __syncthreads();
    int* cur = sca; int* alt = scb;
    for (int off = 1; off < 256; off <<= 1) {
        int x = cur[tid];
        if (tid >= off) x += cur[tid - off];
        alt[tid] = x;
        __syncthreads();
        int* tmp = cur; cur = alt; alt = tmp;
    }
    alt[tid] = cur[tid] - h;          // exclusive base per bucket
    if (tid < NBS && h > 0) gpos[tid] = atomicAdd(&bc[tid], h);
    __syncthreads();
    int* basep = alt;
#pragma unroll
    for (int i = 0; i < 16; i++) {
        if (myg[i] >= 0) {
            int p = basep[myg[i]] + myrank[i];
            stg[p] = myp[i];
            gstg[p] = (unsigned char)myg[i];
        }
    }
    __syncthreads();
    int tot = cur[255];
    for (int i = tid; i < tot; i += 256) {
        int g = gstg[i];
        int o = g * BKT_CAP + gpos[g] + (i - basep[g]);
        region[o] = stg[i];
    }
}

// -------------------- bbase: scan 98 window totals per side ----------------
__global__ void bbase_kernel(const int* __restrict__ bcur, int* __restrict__ bbase,
                             int* __restrict__ rs_u, int* __restrict__ rs_r) {
    __shared__ int a[128], b[128];
    int sidx = blockIdx.x;
    const int* bc = bcur + sidx * NBS;
    int* bb = bbase + sidx * NBS;
    int tid = threadIdx.x;
    a[tid] = (tid < NBS) ? bc[tid] : 0;
    __syncthreads();
    int* cur = a; int* alt = b;
    for (int off = 1; off < 128; off <<= 1) {
        int t = cur[tid];
        if (tid >= off) t += cur[tid - off];
        alt[tid] = t;
        __syncthreads();
        int* tmp = cur; cur = alt; alt = tmp;
    }
    if (tid < NBS) bb[tid] = (tid == 0) ? 0 : cur[tid - 1];
    if (tid == 0) { if (sidx == 0) rs_u[NU] = NE; else rs_r[NR] = NE; }
}

// -------------------- fillpass: per-window count/scan/scatter in LDS -------
__global__ __launch_bounds__(256)
void fillpass_kernel(const int2* __restrict__ pairs, const int* __restrict__ bcur,
                     const int* __restrict__ bbase,
                     int* __restrict__ rs_u, int* __restrict__ rs_r,
                     int* __restrict__ csr_u, int* __restrict__ csr_r) {
    __shared__ int win[BKT_CAP];      // 96 KB CSR window image
    __shared__ int lcnt[2048];        // 8 KB
    __shared__ int lofs[2048];        // 8 KB
    __shared__ int tsc[256], tsc2[256];
    int side = (blockIdx.x >= NBS) ? 1 : 0;
    int bkt = side ? (blockIdx.x - NBS) : blockIdx.x;
    const int2* reg = pairs + ((size_t)side * NBS + bkt) * BKT_CAP;
    int* rs = side ? rs_r : rs_u;
    int* csr = side ? csr_r : csr_u;
    int W = side ? 512 : 2048;
    int lw = side ? LW_R : LW_U;
    int n = side ? NR : NU;
    int d0 = bkt << lw;
    int tot = bcur[side * NBS + bkt];
    int base = bbase[side * NBS + bkt];
    int tid = threadIdx.x;
    for (int i = tid; i < W; i += 256) lcnt[i] = 0;
    __syncthreads();
    // pass 1: local degree count
    for (int i = tid; i < tot; i += 256) {
        int2 p = reg[i];
        atomicAdd(&lcnt[p.y - d0], 1);
    }
    __syncthreads();
    // exclusive scan of W counters (thread-chunked + block scan)
    int per = W >> 8;                 // 8 (user) or 2 (rest)
    int b0 = tid * per;
    int run = 0;
    for (int i = 0; i < per; i++) { int v = lcnt[b0 + i]; lofs[b0 + i] = run; run += v; }
    tsc[tid] = run;
    __syncthreads();
    int* cur = tsc; int* alt = tsc2;
    for (int off = 1; off < 256; off <<= 1) {
        int x = cur[tid];
        if (tid >= off) x += cur[tid - off];
        alt[tid] = x;
        __syncthreads();
        int* tmp = cur; cur = alt; alt = tmp;
    }
    int texcl = cur[tid] - run;
    for (int i = 0; i < per; i++) lofs[b0 + i] += texcl;
    __syncthreads();
    // write rs window (coalesced)
    int wn = min(W, n - d0);
    for (int i = tid; i < wn; i += 256) rs[d0 + i] = base + lofs[i];
    __syncthreads();
    // pass 2: slot assignment via LDS cursor + LDS scatter
    for (int i = tid; i < tot; i += 256) {
        int2 p = reg[i];
        int slot = atomicAdd(&lofs[p.y - d0], 1);
        win[slot] = p.x;
    }
    __syncthreads();
    // stream out (coalesced)
    for (int i = tid; i < tot; i += 256) csr[base + i] = win[i];
}

// -------------------- fused gather mean: wave per dst row, 16x4 groups -----
// 4-deep independent float4 loads per batch (16 neighbors) for MLP; guards
// via degenerate last-neighbor index (loads safe, adds masked).
__global__ __launch_bounds__(256)
void gather2_kernel(const float* __restrict__ hu, const int* __restrict__ csr_r,
                    const int* __restrict__ rs_r, float* __restrict__ mean_r,
                    const float* __restrict__ hr, const int* __restrict__ csr_u,
                    const int* __restrict__ rs_u, float* __restrict__ mean_u) {
    int lane = threadIdx.x & 63;
    int wave = blockIdx.x * 4 + (threadIdx.x >> 6);
    const float* h; const int* csr; const int* rs; float* mean; int r;
    if (wave < NR) { h = hu; csr = csr_r; rs = rs_r; mean = mean_r; r = wave; }
    else if (wave < NR + NU) { h = hr; csr = csr_u; rs = rs_u; mean = mean_u; r = wave - NR; }
    else return;
    int s = rs[r], e = rs[r + 1];
    int g = lane >> 4;            // neighbor subgroup 0..3
    int fo = (lane & 15) << 2;    // feature offset 0,4,...,60
    float4 a0 = {0.f, 0.f, 0.f, 0.f};
    float4 a1 = {0.f, 0.f, 0.f, 0.f};
    float4 a2 = {0.f, 0.f, 0.f, 0.f};
    float4 a3 = {0.f, 0.f, 0.f, 0.f};
    for (int j = s; j < e; j += 64) {
        int rem = e - j;
        int nch = rem < 64 ? rem : 64;
        int li = lane < nch ? lane : nch - 1;
        int idx = csr[j + li];
#pragma unroll 2
        for (int kk = 0; kk < nch; kk += 16) {
            int j0 = kk + g;          // <= 51
            int j1 = kk + 4 + g;      // <= 55
            int j2 = kk + 8 + g;      // <= 59
            int j3 = kk + 12 + g;     // <= 63
            int i0 = __shfl(idx, j0);
            int i1 = __shfl(idx, j1);
            int i2 = __shfl(idx, j2);
            int i3 = __shfl(idx, j3);
            float4 x0 = *(const float4*)(h + (size_t)i0 * DD + fo);
            float4 x1 = *(const float4*)(h + (size_t)i1 * DD + fo);
            float4 x2 = *(const float4*)(h + (size_t)i2 * DD + fo);
            float4 x3 = *(const float4*)(h + (size_t)i3 * DD + fo);
            if (j0 < nch) { a0.x += x0.x; a0.y += x0.y; a0.z += x0.z; a0.w += x0.w; }
            if (j1 < nch) { a1.x += x1.x; a1.y += x1.y; a1.z += x1.z; a1.w += x1.w; }
            if (j2 < nch) { a2.x += x2.x; a2.y += x2.y; a2.z += x2.z; a2.w += x2.w; }
            if (j3 < nch) { a3.x += x3.x; a3.y += x3.y; a3.z += x3.z; a3.w += x3.w; }
        }
    }
    float4 acc;
    acc.x = (a0.x + a1.x) + (a2.x + a3.x);
    acc.y = (a0.y + a1.y) + (a2.y + a3.y);
    acc.z = (a0.z + a1.z) + (a2.z + a3.z);
    acc.w = (a0.w + a1.w) + (a2.w + a3.w);
    acc.x += __shfl_xor(acc.x, 16); acc.y += __shfl_xor(acc.y, 16);
    acc.z += __shfl_xor(acc.z, 16); acc.w += __shfl_xor(acc.w, 16);
    acc.x += __shfl_xor(acc.x, 32); acc.y += __shfl_xor(acc.y, 32);
    acc.z += __shfl_xor(acc.z, 32); acc.w += __shfl_xor(acc.w, 32);
    if (g == 0) {
        float inv = 1.0f / fmaxf((float)(e - s), 1.0f);
        acc.x *= inv; acc.y *= inv; acc.z *= inv; acc.w *= inv;
        *(float4*)(mean + (size_t)r * DD + fo) = acc;
    }
}

#define DOT4(A, B) ((A).x*(B).x + (A).y*(B).y + (A).z*(B).z + (A).w*(B).w)

// -------------------- fused SAGE linear: LDS-staged row tiles --------------
// 4 chunks of 64 rows/block. Stage = coalesced float4; compute = 4rowx4col
// per thread from LDS (W reads 16-lane broadcast, row reads 4-lane bcast).
__global__ __launch_bounds__(256, 2)
void sage_fused_kernel(const float* __restrict__ mean_r, const float* __restrict__ hr,
                       const float* __restrict__ mean_u, const float* __restrict__ hu,
                       const float* __restrict__ Wl2, const float* __restrict__ Wr2,
                       const float* __restrict__ bl2,
                       float* __restrict__ out_r, float* __restrict__ out_u, int do_relu) {
    __shared__ __attribute__((aligned(16))) float Wls[DD * LDW];
    __shared__ __attribute__((aligned(16))) float Wrs[DD * LDW];
    __shared__ __attribute__((aligned(16))) float Ms[64 * LDW];
    __shared__ __attribute__((aligned(16))) float Xs[64 * LDW];
    __shared__ float bsh[DD];
    int side = (blockIdx.x < NBR) ? 0 : 1;
    const float* Wl = Wl2 + side * DD * DD;
    const float* Wr = Wr2 + side * DD * DD;
    const float* bl = bl2 + side * DD;
    const float* mean; const float* h; float* out; int n; int blk;
    if (side == 0) { mean = mean_r; h = hr; out = out_r; n = NR; blk = blockIdx.x; }
    else { mean = mean_u; h = hu; out = out_u; n = NU; blk = blockIdx.x - NBR; }
    int tid = threadIdx.x;
    for (int i = tid; i < DD * DD; i += 256) {
        int c = i >> 6, k = i & 63;
        Wls[c * LDW + k] = Wl[i];
        Wrs[c * LDW + k] = Wr[i];
    }
    if (tid < DD) bsh[tid] = bl[tid];
    int rgrp = tid & 15;
    int cgrp = tid >> 4;
    int cb = cgrp * 4;
    int r00 = blk * 256;
    for (int ch = 0; ch < 4; ch++) {
        int rc0 = r00 + ch * 64;
        __syncthreads();   // LDS reuse guard (also covers W load on ch=0)
        for (int i = tid; i < 1024; i += 256) {
            int row = i >> 4;
            int c4 = (i & 15) << 2;
            int gr = min(rc0 + row, n - 1);
            *(float4*)&Ms[row * LDW + c4] = *(const float4*)(mean + (size_t)gr * DD + c4);
            *(float4*)&Xs[row * LDW + c4] = *(const float4*)(h + (size_t)gr * DD + c4);
        }
        __syncthreads();
        float4 bias = {bsh[cb], bsh[cb + 1], bsh[cb + 2], bsh[cb + 3]};
        float4 acc0 = bias, acc1 = bias, acc2 = bias, acc3 = bias;
#pragma unroll 1
        for (int kc = 0; kc < DD; kc += 8) {
            float4 wl[4][2], wr[4][2];
#pragma unroll
            for (int c = 0; c < 4; c++) {
                wl[c][0] = *(const float4*)&Wls[(cb + c) * LDW + kc];
                wl[c][1] = *(const float4*)&Wls[(cb + c) * LDW + kc + 4];
                wr[c][0] = *(const float4*)&Wrs[(cb + c) * LDW + kc];
                wr[c][1] = *(const float4*)&Wrs[(cb + c) * LDW + kc + 4];
            }
#define SROW(J, ACC) { \
            int row_ = rgrp + 16 * (J); \
            float4 ma_ = *(const float4*)&Ms[row_ * LDW + kc]; \
            float4 mb_ = *(const float4*)&Ms[row_ * LDW + kc + 4]; \
            float4 xa_ = *(const float4*)&Xs[row_ * LDW + kc]; \
            float4 xb_ = *(const float4*)&Xs[row_ * LDW + kc + 4]; \
            ACC.x += DOT4(ma_,wl[0][0])+DOT4(mb_,wl[0][1])+DOT4(xa_,wr[0][0])+DOT4(xb_,wr[0][1]); \
            ACC.y += DOT4(ma_,wl[1][0])+DOT4(mb_,wl[1][1])+DOT4(xa_,wr[1][0])+DOT4(xb_,wr[1][1]); \
            ACC.z += DOT4(ma_,wl[2][0])+DOT4(mb_,wl[2][1])+DOT4(xa_,wr[2][0])+DOT4(xb_,wr[2][1]); \
            ACC.w += DOT4(ma_,wl[3][0])+DOT4(mb_,wl[3][1])+DOT4(xa_,wr[3][0])+DOT4(xb_,wr[3][1]); }
            SROW(0, acc0) SROW(1, acc1) SROW(2, acc2) SROW(3, acc3)
#undef SROW
        }
        if (do_relu) {
            acc0.x = fmaxf(acc0.x, 0.f); acc0.y = fmaxf(acc0.y, 0.f); acc0.z = fmaxf(acc0.z, 0.f); acc0.w = fmaxf(acc0.w, 0.f);
            acc1.x = fmaxf(acc1.x, 0.f); acc1.y = fmaxf(acc1.y, 0.f); acc1.z = fmaxf(acc1.z, 0.f); acc1.w = fmaxf(acc1.w, 0.f);
            acc2.x = fmaxf(acc2.x, 0.f); acc2.y = fmaxf(acc2.y, 0.f); acc2.z = fmaxf(acc2.z, 0.f); acc2.w = fmaxf(acc2.w, 0.f);
            acc3.x = fmaxf(acc3.x, 0.f); acc3.y = fmaxf(acc3.y, 0.f); acc3.z = fmaxf(acc3.z, 0.f); acc3.w = fmaxf(acc3.w, 0.f);
        }
        {
            int r0_ = rc0 + rgrp;
            if (r0_ < n)      *(float4*)(out + (size_t)r0_ * DD + cb) = acc0;
            if (r0_ + 16 < n) *(float4*)(out + (size_t)(r0_ + 16) * DD + cb) = acc1;
            if (r0_ + 32 < n) *(float4*)(out + (size_t)(r0_ + 32) * DD + cb) = acc2;
            if (r0_ + 48 < n) *(float4*)(out + (size_t)(r0_ + 48) * DD + cb) = acc3;
        }
    }
}

// -------------------- fused decoder layer-1 precompute (LDS-staged) --------
__global__ __launch_bounds__(256, 2)
void pre_fused_kernel(const float* __restrict__ hu, const float* __restrict__ hr,
                      const float* __restrict__ dW1, const float* __restrict__ db1,
                      float* __restrict__ P_u, float* __restrict__ P_r) {
    __shared__ __attribute__((aligned(16))) float Ws[DD * LDW];
    __shared__ __attribute__((aligned(16))) float Xs[64 * LDW];
    __shared__ float bsh[DD];
    int side = (blockIdx.x < NBU) ? 0 : 1;   // 0 = user (koff 0, bias), 1 = rest
    int koff = side ? DD : 0;
    const float* h; float* out; int n; int blk;
    if (side == 0) { h = hu; out = P_u; n = NU; blk = blockIdx.x; }
    else { h = hr; out = P_r; n = NR; blk = blockIdx.x - NBU; }
    int tid = threadIdx.x;
    for (int i = tid; i < DD * DD; i += 256) {
        int c = i >> 6, k = i & 63;
        Ws[c * LDW + k] = dW1[c * 2 * DD + koff + k];
    }
    if (tid < DD) bsh[tid] = side ? 0.f : db1[tid];
    int rgrp = tid & 15;
    int cgrp = tid >> 4;
    int cb = cgrp * 4;
    int r00 = blk * 256;
    for (int ch = 0; ch < 4; ch++) {
        int rc0 = r00 + ch * 64;
        __syncthreads();
        for (int i = tid; i < 1024; i += 256) {
            int row = i >> 4;
            int c4 = (i & 15) << 2;
            int gr = min(rc0 + row, n - 1);
            *(float4*)&Xs[row * LDW + c4] = *(const float4*)(h + (size_t)gr * DD + c4);
        }
        __syncthreads();
        float4 bias = {bsh[cb], bsh[cb + 1], bsh[cb + 2], bsh[cb + 3]};
        float4 acc0 = bias, acc1 = bias, acc2 = bias, acc3 = bias;
#pragma unroll 1
        for (int kc = 0; kc < DD; kc += 8) {
            float4 wv[4][2];
#pragma unroll
            for (int c = 0; c < 4; c++) {
                wv[c][0] = *(const float4*)&Ws[(cb + c) * LDW + kc];
                wv[c][1] = *(const float4*)&Ws[(cb + c) * LDW + kc + 4];
            }
#define PROW(J, ACC) { \
            int row_ = rgrp + 16 * (J); \
            float4 xa_ = *(const float4*)&Xs[row_ * LDW + kc]; \
            float4 xb_ = *(const float4*)&Xs[row_ * LDW + kc + 4]; \
            ACC.x += DOT4(xa_,wv[0][0])+DOT4(xb_,wv[0][1]); \
            ACC.y += DOT4(xa_,wv[1][0])+DOT4(xb_,wv[1][1]); \
            ACC.z += DOT4(xa_,wv[2][0])+DOT4(xb_,wv[2][1]); \
            ACC.w += DOT4(xa_,wv[3][0])+DOT4(xb_,wv[3][1]); }
            PROW(0, acc0) PROW(1, acc1) PROW(2, acc2) PROW(3, acc3)
#undef PROW
        }
        {
            int r0_ = rc0 + rgrp;
            if (r0_ < n)      *(float4*)(out + (size_t)r0_ * DD + cb) = acc0;
            if (r0_ + 16 < n) *(float4*)(out + (size_t)(r0_ + 16) * DD + cb) = acc1;
            if (r0_ + 32 < n) *(float4*)(out + (size_t)(r0_ + 32) * DD + cb) = acc2;
            if (r0_ + 48 < n) *(float4*)(out + (size_t)(r0_ + 48) * DD + cb) = acc3;
        }
    }
}

// -------------------- fused decoder: thread per query (R8 form) ------------
#define ZCOMB(Zi, i) float4 Zi; { float4 u_ = pu[i]; float4 v_ = pr[i]; \
    Zi.x = fmaxf(u_.x + v_.x, 0.f); Zi.y = fmaxf(u_.y + v_.y, 0.f); \
    Zi.z = fmaxf(u_.z + v_.z, 0.f); Zi.w = fmaxf(u_.w + v_.w, 0.f); }

__global__ __launch_bounds__(256, 2)
void decoder_kernel(const float* __restrict__ Pu, const float* __restrict__ Pr,
                    const int* __restrict__ el_row, const int* __restrict__ el_col,
                    const float* __restrict__ dW2, const float* __restrict__ db2,
                    const float* __restrict__ dW3, const float* __restrict__ db3,
                    float* __restrict__ out) {
    __shared__ float W2s[DD * DD];
    __shared__ float b2s[DD], w3s[DD];
    for (int i = threadIdx.x; i < DD * DD; i += 256) W2s[i] = dW2[i];
    if (threadIdx.x < DD) {
        b2s[threadIdx.x] = db2[threadIdx.x];
        w3s[threadIdx.x] = dW3[threadIdx.x];
    }
    __syncthreads();
    int q = blockIdx.x * 256 + threadIdx.x;
    if (q >= NQ) return;
    int row = el_row[q], col = el_col[q];
    const float4* pu = (const float4*)(Pu + (size_t)row * DD);
    const float4* pr = (const float4*)(Pr + (size_t)col * DD);
    ZCOMB(z0, 0)  ZCOMB(z1, 1)  ZCOMB(z2, 2)  ZCOMB(z3, 3)
    ZCOMB(z4, 4)  ZCOMB(z5, 5)  ZCOMB(z6, 6)  ZCOMB(z7, 7)
    ZCOMB(z8, 8)  ZCOMB(z9, 9)  ZCOMB(z10, 10) ZCOMB(z11, 11)
    ZCOMB(z12, 12) ZCOMB(z13, 13) ZCOMB(z14, 14) ZCOMB(z15, 15)
    float o = db3[0];
#pragma unroll 2
    for (int c = 0; c < DD; c++) {
        const float4* wp = (const float4*)(W2s + c * DD);  // broadcast, conflict-free
        float s = b2s[c]
            + DOT4(z0, wp[0])  + DOT4(z1, wp[1])  + DOT4(z2, wp[2])  + DOT4(z3, wp[3])
            + DOT4(z4, wp[4])  + DOT4(z5, wp[5])  + DOT4(z6, wp[6])  + DOT4(z7, wp[7])
            + DOT4(z8, wp[8])  + DOT4(z9, wp[9])  + DOT4(z10, wp[10]) + DOT4(z11, wp[11])
            + DOT4(z12, wp[12]) + DOT4(z13, wp[13]) + DOT4(z14, wp[14]) + DOT4(z15, wp[15]);
        o += fmaxf(s, 0.f) * w3s[c];
    }
    out[q] = o;
}

extern "C" void kernel_launch(void* const* d_in, const int* in_sizes, int n_in,
                              void* d_out, int out_size, void* d_ws, size_t ws_size,
                              hipStream_t stream) {
    const float* x_user = (const float*)d_in[0];
    const float* x_rest = (const float*)d_in[1];
    const float* Wl     = (const float*)d_in[2];
    const float* Wr     = (const float*)d_in[3];
    const float* bl     = (const float*)d_in[4];
    const float* dW1    = (const float*)d_in[5];
    const float* db1    = (const float*)d_in[6];
    const float* dW2    = (const float*)d_in[7];
    const float* db2    = (const float*)d_in[8];
    const float* dW3    = (const float*)d_in[9];
    const float* db3    = (const float*)d_in[10];
    const int* ur_src   = (const int*)d_in[11];
    const int* ur_dst   = (const int*)d_in[12];
    const int* ru_src   = (const int*)d_in[13];
    const int* ru_dst   = (const int*)d_in[14];
    const int* el_row   = (const int*)d_in[15];
    const int* el_col   = (const int*)d_in[16];
    float* out = (float*)d_out;

    char* w = (char*)d_ws;
    size_t off = 0;
    auto alloc = [&](size_t bytes) -> void* {
        void* p = (void*)(w + off);
        off += (bytes + 255) & ~(size_t)255;
        return p;
    };
    float* hu0    = (float*)alloc((size_t)NU * DD * 4);
    float* hu1    = (float*)alloc((size_t)NU * DD * 4);
    float* hr0    = (float*)alloc((size_t)NR * DD * 4);
    float* hr1    = (float*)alloc((size_t)NR * DD * 4);
    float* mean_u = (float*)alloc((size_t)NU * DD * 4);
    float* mean_r = (float*)alloc((size_t)NR * DD * 4);
    int* csr_u  = (int*)alloc((size_t)NE * 4);
    int* csr_r  = (int*)alloc((size_t)NE * 4);
    int* rs_u   = (int*)alloc((size_t)(NU + 1) * 4);
    int* rs_r   = (int*)alloc((size_t)(NR + 1) * 4);
    int* bcur   = (int*)alloc((size_t)2 * NBS * 4);
    int* bbase  = (int*)alloc((size_t)2 * NBS * 4);

    // pair buffer carved from mean_u (written only later by gather2):
    // 2 * 98 * 24576 * 8B = 38.5MB <= NU*DD*4 = 51.2MB
    int2* pairs = (int2*)mean_u;

    // ---- CSR build: bin by dst window -> window-local count/scan/fill ----
    hipMemsetAsync(bcur, 0, (size_t)2 * NBS * 4, stream);
    binpass_kernel<<<2 * NPBB, 256, 0, stream>>>(ru_src, ru_dst, ur_src, ur_dst,
                                                 bcur, pairs);
    bbase_kernel<<<2, 128, 0, stream>>>(bcur, bbase, rs_u, rs_r);
    fillpass_kernel<<<2 * NBS, 256, 0, stream>>>(pairs, bcur, bbase,
                                                 rs_u, rs_r, csr_u, csr_r);

    // ---- 3 SAGE layers: 2 fused launches per layer ----
    const float* cu = x_user;
    const float* cr = x_rest;
    float* nu_[3] = {hu0, hu1, hu0};
    float* nr_[3] = {hr0, hr1, hr0};
    const int ggrid = (NR + NU + 3) / 4;   // 62500

    for (int l = 0; l < 3; l++) {
        const float* Wl2 = Wl + (size_t)l * 2 * DD * DD;
        const float* Wr2 = Wr + (size_t)l * 2 * DD * DD;
        const float* bl2 = bl + (size_t)l * 2 * DD;
        int relu = (l < 2) ? 1 : 0;
        gather2_kernel<<<ggrid, 256, 0, stream>>>(cu, csr_r, rs_r, mean_r,
                                                  cr, csr_u, rs_u, mean_u);
        sage_fused_kernel<<<NBR + NBU, 256, 0, stream>>>(mean_r, cr, mean_u, cu,
                                                         Wl2, Wr2, bl2,
                                                         nr_[l], nu_[l], relu);
        cu = nu_[l];
        cr = nr_[l];
    }
    // ---- decoder ----
    float* P_u = hu1;
    float* P_r = hr1;
    pre_fused_kernel<<<NBU + NBR, 256, 0, stream>>>(cu, cr, dW1, db1, P_u, P_r);
    decoder_kernel<<<(NQ + 255) / 256, 256, 0, stream>>>(P_u, P_r, el_row, el_col,
                                                         dW2, db2, dW3, db3, out);
}